// Round 7
// baseline (859.633 us; speedup 1.0000x reference)
//
#include <hip/hip_runtime.h>
#include <hip/hip_fp16.h>

typedef unsigned int uint32_ty;

// native vector types
typedef float    nfloat2 __attribute__((ext_vector_type(2)));
typedef float    nfloat4 __attribute__((ext_vector_type(4)));
typedef int      nint4   __attribute__((ext_vector_type(4)));
typedef _Float16 h16x2   __attribute__((ext_vector_type(2)));
typedef _Float16 f16x8   __attribute__((ext_vector_type(8)));
typedef float    f32x4   __attribute__((ext_vector_type(4)));
typedef unsigned short ushort4n __attribute__((ext_vector_type(4)));

// Problem constants
#define BB 4
#define SS 512
#define DD 768
#define HH 12
#define DHH 64
#define SDD 30

// padded LDS row stride (elements) for fp16 rows of length 512
#define LP 520

__device__ __forceinline__ unsigned short toh(float f) {
    _Float16 h = (_Float16)f;
    return __builtin_bit_cast(unsigned short, h);
}
__device__ __forceinline__ float hf(unsigned short u) {
    return (float)__builtin_bit_cast(_Float16, u);
}
// fused 2-wide fp16 dot with f32 accumulate (v_dot2_f32_f16)
__device__ __forceinline__ float dot2(uint32_ty a, uint32_ty b, float c) {
#if __has_builtin(__builtin_amdgcn_fdot2)
    return __builtin_amdgcn_fdot2(__builtin_bit_cast(h16x2, a),
                                  __builtin_bit_cast(h16x2, b), c, false);
#else
    h16x2 x = __builtin_bit_cast(h16x2, a), y = __builtin_bit_cast(h16x2, b);
    return c + (float)x.x * (float)y.x + (float)x.y * (float)y.y;
#endif
}
__device__ __forceinline__ void unp8h(uint4 u, float* t) {
    h16x2 p;
    p = __builtin_bit_cast(h16x2, u.x); t[0] = p.x; t[1] = p.y;
    p = __builtin_bit_cast(h16x2, u.y); t[2] = p.x; t[3] = p.y;
    p = __builtin_bit_cast(h16x2, u.z); t[4] = p.x; t[5] = p.y;
    p = __builtin_bit_cast(h16x2, u.w); t[6] = p.x; t[7] = p.y;
}

// ---------------------------------------------------------------------------
// K1: fused projection GEMMs, MFMA fp16 (f32 accumulate).
// Tile 64x64, BK=64. 4 waves, each a 32x32 quadrant (2x2 of 16x16 frags).
// z=0 -> q fp16 (B,H,S,DH) scaled 1/8; z=1 -> k fp16 (B,H,S,DH) natural;
// z=2 -> vT fp16 (B,H,DH,S).
// ---------------------------------------------------------------------------
#define MBM 64
#define MBN 64
#define MBK 64
#define LDK 72

__global__ __launch_bounds__(256) void gemm_proj3(
    const float* __restrict__ Xq, const float* __restrict__ Xk, const float* __restrict__ Xv,
    const float* __restrict__ Wq, const float* __restrict__ Wk, const float* __restrict__ Wv,
    const float* __restrict__ bq, const float* __restrict__ bk, const float* __restrict__ bv,
    unsigned short* __restrict__ oq, unsigned short* __restrict__ ok,
    unsigned short* __restrict__ ovT)
{
    __shared__ unsigned short As[MBM][LDK];   // [m][k] fp16
    __shared__ unsigned short Bs[MBN][LDK];   // [n][k] fp16
    int z = blockIdx.z;
    const float* X = (z == 0) ? Xq : (z == 1) ? Xk : Xv;
    const float* W = (z == 0) ? Wq : (z == 1) ? Wk : Wv;
    const float* bias = (z == 0) ? bq : (z == 1) ? bk : bv;

    int tid = threadIdx.x;
    int lane = tid & 63, wave = tid >> 6;
    int m0 = blockIdx.y * MBM, n0 = blockIdx.x * MBN;
    int wm = (wave >> 1) * 32, wn = (wave & 1) * 32;
    int fr = lane & 15, fq = lane >> 4;

    f32x4 acc[2][2];
#pragma unroll
    for (int i = 0; i < 2; i++)
#pragma unroll
        for (int j = 0; j < 2; j++) acc[i][j] = (f32x4){0.f, 0.f, 0.f, 0.f};

    for (int k0 = 0; k0 < DD; k0 += MBK) {
#pragma unroll
        for (int rep = 0; rep < 4; rep++) {
            int i = tid + 256 * rep;
            int r = i >> 4, c4 = i & 15;
            float4 xv = *(const float4*)(X + (size_t)(m0 + r) * DD + k0 + 4 * c4);
            ushort4n pk = {toh(xv.x), toh(xv.y), toh(xv.z), toh(xv.w)};
            *(ushort4n*)&As[r][4 * c4] = pk;
        }
#pragma unroll
        for (int rep = 0; rep < 4; rep++) {
            int i = tid + 256 * rep;
            int r = i >> 4, c4 = i & 15;
            float4 wv = *(const float4*)(W + (size_t)(k0 + r) * DD + n0 + 4 * c4);
            Bs[4 * c4 + 0][r] = toh(wv.x);
            Bs[4 * c4 + 1][r] = toh(wv.y);
            Bs[4 * c4 + 2][r] = toh(wv.z);
            Bs[4 * c4 + 3][r] = toh(wv.w);
        }
        __syncthreads();
#pragma unroll
        for (int ks = 0; ks < 2; ks++) {
            f16x8 a0 = *(f16x8*)&As[wm + fr][ks * 32 + fq * 8];
            f16x8 a1 = *(f16x8*)&As[wm + 16 + fr][ks * 32 + fq * 8];
            f16x8 b0 = *(f16x8*)&Bs[wn + fr][ks * 32 + fq * 8];
            f16x8 b1 = *(f16x8*)&Bs[wn + 16 + fr][ks * 32 + fq * 8];
            acc[0][0] = __builtin_amdgcn_mfma_f32_16x16x32_f16(a0, b0, acc[0][0], 0, 0, 0);
            acc[0][1] = __builtin_amdgcn_mfma_f32_16x16x32_f16(a0, b1, acc[0][1], 0, 0, 0);
            acc[1][0] = __builtin_amdgcn_mfma_f32_16x16x32_f16(a1, b0, acc[1][0], 0, 0, 0);
            acc[1][1] = __builtin_amdgcn_mfma_f32_16x16x32_f16(a1, b1, acc[1][1], 0, 0, 0);
        }
        __syncthreads();
    }

    // C/D layout: col=lane&15, row=(lane>>4)*4+r (dtype-independent, R6-verified)
#pragma unroll
    for (int i = 0; i < 2; i++) {
#pragma unroll
        for (int j = 0; j < 2; j++) {
            int n = n0 + wn + 16 * j + fr;
            int h = n >> 6, d = n & 63;
            float bn = bias[n];
            int mbase = m0 + wm + 16 * i + fq * 4;
            int b = mbase >> 9, sbase = mbase & 511;
            if (z == 2) {
                ushort4n pk;
#pragma unroll
                for (int r = 0; r < 4; r++) pk[r] = toh(acc[i][j][r] + bn);
                *(ushort4n*)(ovT + ((((size_t)b * HH + h) * DHH + d) * SS + sbase)) = pk;
            } else if (z == 0) {
#pragma unroll
                for (int r = 0; r < 4; r++)
                    oq[((((size_t)b * HH + h) * SS + sbase + r) * DHH + d)] =
                        toh((acc[i][j][r] + bn) * 0.125f);
            } else {
#pragma unroll
                for (int r = 0; r < 4; r++)
                    ok[((((size_t)b * HH + h) * SS + sbase + r) * DHH + d)] =
                        toh(acc[i][j][r] + bn);
            }
        }
    }
}

// ---------------------------------------------------------------------------
// K3: output GEMM  out = ctx @ Wo + bo  (f32, R2-proven, unchanged)
// ---------------------------------------------------------------------------
#define TM 64
#define TN 64
#define TKK 32

__global__ __launch_bounds__(256) void gemm_out(
    const float* __restrict__ Xf, const float* __restrict__ W,
    const float* __restrict__ bias, float* __restrict__ out)
{
    __shared__ float As[TKK][TM + 4];
    __shared__ float Bs[TKK][TN + 4];
    int tx = threadIdx.x, ty = threadIdx.y;
    int tid = ty * 16 + tx;
    int m0 = blockIdx.y * TM;
    int n0 = blockIdx.x * TN;
    float acc[4][4] = {};
    for (int k0 = 0; k0 < DD; k0 += TKK) {
#pragma unroll
        for (int rep = 0; rep < 2; rep++) {
            int f = tid + 256 * rep;
            int r = f >> 3, c = f & 7;
            float4 xv = *(const float4*)(Xf + (size_t)(m0 + r) * DD + k0 + 4 * c);
            As[4 * c + 0][r] = xv.x; As[4 * c + 1][r] = xv.y;
            As[4 * c + 2][r] = xv.z; As[4 * c + 3][r] = xv.w;
        }
#pragma unroll
        for (int rep = 0; rep < 2; rep++) {
            int f = tid + 256 * rep;
            int r = f >> 4, c = f & 15;
            float4 wv = *(const float4*)(W + (size_t)(k0 + r) * DD + n0 + 4 * c);
            *(float4*)&Bs[r][4 * c] = wv;
        }
        __syncthreads();
#pragma unroll 8
        for (int kk = 0; kk < TKK; kk++) {
            float4 av = *(float4*)&As[kk][ty * 4];
            float4 bv4 = *(float4*)&Bs[kk][tx * 4];
            float a[4] = {av.x, av.y, av.z, av.w};
            float bb[4] = {bv4.x, bv4.y, bv4.z, bv4.w};
#pragma unroll
            for (int i = 0; i < 4; i++)
#pragma unroll
                for (int j = 0; j < 4; j++) acc[i][j] += a[i] * bb[j];
        }
        __syncthreads();
    }
#pragma unroll
    for (int i = 0; i < 4; i++) {
        int m = m0 + ty * 4 + i;
#pragma unroll
        for (int j = 0; j < 4; j++) {
            int n = n0 + tx * 4 + j;
            out[(size_t)m * DD + n] = acc[i][j] + bias[n];
        }
    }
}

// ---------------------------------------------------------------------------
// K2 (fused attention) v5: fp16 pipeline + v_dot2_f32_f16 in all reduction
// loops. k natural (S,DH); v transposed (DH,S); at/stT fp16 in LDS.
// kpos owned by lane = 8*lane..8*lane+7 (R5-proven mapping).
// ---------------------------------------------------------------------------
__global__ __launch_bounds__(256) void attn_fused(
    const unsigned short* __restrict__ q,  // (B,H,S,DH) fp16
    const unsigned short* __restrict__ k,  // (B,H,S,DH) fp16
    const unsigned short* __restrict__ vT, // (B,H,DH,S) fp16
    const float* __restrict__ structure,   // (B,S,S,30) f32
    const int* __restrict__ mask,          // (B,S,S) int32 0/1
    const float* __restrict__ Wsk,  // (30,64)
    const float* __restrict__ bsk,  // (64)
    const float* __restrict__ Wsv,  // (30,64)
    const float* __restrict__ bsv,  // (64)
    float* __restrict__ ctx,        // (B,S,D)
    float* __restrict__ top_attn)   // (B,S,S) f32
{
    __shared__ uint32_ty qs32[HH * 32];         //  1536 B  q rows fp16-packed
    __shared__ unsigned short stT[SDD][LP];     // 31200 B  structure row^T fp16
    __shared__ float qt_s[HH][SDD];             //  1440 B
    __shared__ float qb_s[HH];                  //    48 B
    __shared__ float astr_s[HH][SDD];           //  1440 B
    __shared__ unsigned short at[HH][LP];       // 12480 B  attn weights fp16 [h][k]

    int tid = threadIdx.x;
    int lane = tid & 63, wave = tid >> 6;

    // XCD-aware swizzle: blocks on one XCD share one batch's k/v slab
    int blk = blockIdx.x;
    int xcd = blk & 7;
    int b = xcd >> 1;
    int qp = ((xcd & 1) << 8) | (blk >> 3);

    // --- load q rows (fp16 dword copies) ---
    for (int i = tid; i < HH * 32; i += 256) {
        int h = i >> 5, c = i & 31;
        qs32[i] = *(const uint32_ty*)(q + (((size_t)b * HH + h) * SS + qp) * DHH + 2 * c);
    }
    // --- structure row (b,qp,:,:) f32 -> transposed fp16 LDS (R2/R5 pattern) ---
    {
        const float* srow = structure + ((size_t)b * SS + qp) * (size_t)(SS * SDD);
        for (int kk = tid; kk < SS; kk += 256) {
            const nfloat2* rp = (const nfloat2*)(srow + (size_t)kk * SDD);
#pragma unroll
            for (int w = 0; w < 15; w++) {
                nfloat2 xv = __builtin_nontemporal_load(rp + w);
                stT[2 * w][kk] = toh(xv.x);
                stT[2 * w + 1][kk] = toh(xv.y);
            }
        }
    }
    __syncthreads();

    // --- qt[h][si] = q[h] . Wsk[si]; qb[h] = q[h] . bsk ---
    for (int i = tid; i < HH * SDD; i += 256) {
        int h = i / SDD, si = i % SDD;
        const uint32_ty* qp32 = &qs32[h * 32];
        const float* wp = Wsk + si * DHH;
        float a = 0.f;
#pragma unroll
        for (int c = 0; c < 32; c++) {
            h16x2 p = __builtin_bit_cast(h16x2, qp32[c]);
            a += (float)p.x * wp[2 * c] + (float)p.y * wp[2 * c + 1];
        }
        qt_s[h][si] = a;
    }
    if (tid < HH) {
        const uint32_ty* qp32 = &qs32[tid * 32];
        float a = 0.f;
#pragma unroll
        for (int c = 0; c < 32; c++) {
            h16x2 p = __builtin_bit_cast(h16x2, qp32[c]);
            a += (float)p.x * bsk[2 * c] + (float)p.y * bsk[2 * c + 1];
        }
        qb_s[tid] = a;
    }
    __syncthreads();

    // --- scores: wave w -> heads 3w..3w+2, lane owns kpos = 8*lane..8*lane+7 ---
    int h0 = wave * 3;
    float attnv[3][8];
#pragma unroll
    for (int h = 0; h < 3; h++)
#pragma unroll
        for (int j = 0; j < 8; j++) attnv[h][j] = 0.f;

    // structure-score term: b128 stT reads, broadcast qt
#pragma unroll 2
    for (int si = 0; si < SDD; si++) {
        uint4 sv4 = *(const uint4*)&stT[si][8 * lane];
        float t[8];
        unp8h(sv4, t);
#pragma unroll
        for (int h = 0; h < 3; h++) {
            float qt = qt_s[h0 + h][si];
#pragma unroll
            for (int j = 0; j < 8; j++) attnv[h][j] += qt * t[j];
        }
    }

    // q.k term via dot2: lane streams its 8 k-rows (128B each, L1-resident)
#pragma unroll
    for (int h = 0; h < 3; h++) {
        const unsigned short* kh = k + (size_t)((size_t)b * HH + h0 + h) * SS * DHH;
        const uint4* qp4 = (const uint4*)&qs32[(h0 + h) * 32];
        uint4 qr[8];
#pragma unroll
        for (int c = 0; c < 8; c++) qr[c] = qp4[c];
        float qb = qb_s[h0 + h];
#pragma unroll
        for (int j = 0; j < 8; j++) {
            const uint4* kr = (const uint4*)(kh + (size_t)(8 * lane + j) * DHH);
            float s0 = 0.f, s1 = 0.f, s2 = 0.f, s3 = 0.f;
#pragma unroll
            for (int c = 0; c < 8; c++) {
                uint4 kv = kr[c];
                s0 = dot2(qr[c].x, kv.x, s0);
                s1 = dot2(qr[c].y, kv.y, s1);
                s2 = dot2(qr[c].z, kv.z, s2);
                s3 = dot2(qr[c].w, kv.w, s3);
            }
            attnv[h][j] += s0 + s1 + s2 + s3 + qb;
        }
    }

    // mask
    {
        const int* mrow = mask + ((size_t)b * SS + qp) * SS + 8 * lane;
        nint4 m0v = __builtin_nontemporal_load((const nint4*)mrow);
        nint4 m1v = __builtin_nontemporal_load(((const nint4*)mrow) + 1);
        int mm[8] = {m0v.x, m0v.y, m0v.z, m0v.w, m1v.x, m1v.y, m1v.z, m1v.w};
#pragma unroll
        for (int h = 0; h < 3; h++)
#pragma unroll
            for (int j = 0; j < 8; j++)
                if (mm[j]) attnv[h][j] = -1e18f;
    }

    // --- softmax per head, in-wave ---
#pragma unroll
    for (int h = 0; h < 3; h++) {
        float m = attnv[h][0];
#pragma unroll
        for (int j = 1; j < 8; j++) m = fmaxf(m, attnv[h][j]);
#pragma unroll
        for (int off = 32; off > 0; off >>= 1) m = fmaxf(m, __shfl_xor(m, off));
        float l = 0.f;
#pragma unroll
        for (int j = 0; j < 8; j++) { attnv[h][j] = __expf(attnv[h][j] - m); l += attnv[h][j]; }
#pragma unroll
        for (int off = 32; off > 0; off >>= 1) l += __shfl_xor(l, off);
        float inv = 1.f / l;
        float a[8];
#pragma unroll
        for (int j = 0; j < 8; j++) a[j] = attnv[h][j] * inv;
        uint4 pk;
        pk.x = (uint32_ty)toh(a[0]) | ((uint32_ty)toh(a[1]) << 16);
        pk.y = (uint32_ty)toh(a[2]) | ((uint32_ty)toh(a[3]) << 16);
        pk.z = (uint32_ty)toh(a[4]) | ((uint32_ty)toh(a[5]) << 16);
        pk.w = (uint32_ty)toh(a[6]) | ((uint32_ty)toh(a[7]) << 16);
        *(uint4*)&at[h0 + h][8 * lane] = pk;
        if (h0 + h == 0) {
            float* tp = top_attn + ((size_t)b * SS + qp) * SS + 8 * lane;
            nfloat4 w0 = {a[0], a[1], a[2], a[3]};
            nfloat4 w1 = {a[4], a[5], a[6], a[7]};
            __builtin_nontemporal_store(w0, (nfloat4*)tp);
            __builtin_nontemporal_store(w1, ((nfloat4*)tp) + 1);
        }
    }
    __syncthreads();

    // --- astr[h][si] = sum_k at[h][k] * stT[si][k] via dot2 ---
    if (tid < 180) {
        int h = tid / 15, sp = tid % 15;
        int si0 = 2 * sp, si1 = si0 + 1;
        float a0 = 0.f, b0 = 0.f, a1 = 0.f, b1 = 0.f;
#pragma unroll 4
        for (int j = 0; j < 64; j++) {
            uint4 av = *(const uint4*)&at[h][8 * j];
            uint4 s0 = *(const uint4*)&stT[si0][8 * j];
            uint4 s1 = *(const uint4*)&stT[si1][8 * j];
            a0 = dot2(av.x, s0.x, a0); b0 = dot2(av.y, s0.y, b0);
            a0 = dot2(av.z, s0.z, a0); b0 = dot2(av.w, s0.w, b0);
            a1 = dot2(av.x, s1.x, a1); b1 = dot2(av.y, s1.y, b1);
            a1 = dot2(av.z, s1.z, a1); b1 = dot2(av.w, s1.w, b1);
        }
        astr_s[h][si0] = a0 + b0;
        astr_s[h][si1] = a1 + b1;
    }
    __syncthreads();

    // --- ctx: o = tid + 256r; attn@vT via dot2 (wave = one h -> at broadcast) ---
#pragma unroll
    for (int r = 0; r < 3; r++) {
        int o = tid + 256 * r;
        int h = o >> 6, d = o & 63;
        const uint4* vr = (const uint4*)(vT + (((size_t)b * HH + h) * DHH + d) * SS);
        float s0 = 0.f, s1 = 0.f, s2 = 0.f, s3 = 0.f;
#pragma unroll 4
        for (int j = 0; j < 64; j++) {
            uint4 av = *(const uint4*)&at[h][8 * j];
            uint4 vv = vr[j];
            s0 = dot2(av.x, vv.x, s0);
            s1 = dot2(av.y, vv.y, s1);
            s2 = dot2(av.z, vv.z, s2);
            s3 = dot2(av.w, vv.w, s3);
        }
        float sa = bsv[d];
#pragma unroll
        for (int si = 0; si < SDD; si++) sa += astr_s[h][si] * Wsv[si * DHH + d];
        ctx[((size_t)b * SS + qp) * DD + o] = s0 + s1 + s2 + s3 + sa;
    }
}

// ---------------------------------------------------------------------------
extern "C" void kernel_launch(void* const* d_in, const int* in_sizes, int n_in,
                              void* d_out, int out_size, void* d_ws, size_t ws_size,
                              hipStream_t stream)
{
    const float* key       = (const float*)d_in[0];
    const float* value     = (const float*)d_in[1];
    const float* query     = (const float*)d_in[2];
    const float* structure = (const float*)d_in[3];
    const int*   mask      = (const int*)d_in[4];
    const float* Wq  = (const float*)d_in[5];
    const float* bq  = (const float*)d_in[6];
    const float* Wk  = (const float*)d_in[7];
    const float* bk  = (const float*)d_in[8];
    const float* Wv  = (const float*)d_in[9];
    const float* bv  = (const float*)d_in[10];
    const float* Wsk = (const float*)d_in[11];
    const float* bsk = (const float*)d_in[12];
    const float* Wsv = (const float*)d_in[13];
    const float* bsv = (const float*)d_in[14];
    const float* Wo  = (const float*)d_in[15];
    const float* bo  = (const float*)d_in[16];

    float* out_main = (float*)d_out;                         // (B,S,D)
    float* out_attn = (float*)d_out + (size_t)BB * SS * DD;  // (B,S,S)

    float* ws = (float*)d_ws;
    unsigned short* q_buf  = (unsigned short*)ws;                 // (B,H,S,DH) fp16
    unsigned short* k_buf  = (unsigned short*)(ws + 786432);      // (B,H,S,DH) fp16
    unsigned short* vT_buf = (unsigned short*)(ws + 1572864);     // (B,H,DH,S) fp16
    float*          ctx_buf = ws + 2359296;                       // (B,S,D) f32

    dim3 ggrd3(DD / MBN, (BB * SS) / MBM, 3);   // 12 x 32 x 3
    gemm_proj3<<<ggrd3, dim3(256), 0, stream>>>(query, key, value, Wq, Wk, Wv,
                                                bq, bk, bv, q_buf, k_buf, vT_buf);

    attn_fused<<<BB * SS, 256, 0, stream>>>(q_buf, k_buf, vT_buf, structure, mask,
                                            Wsk, bsk, Wsv, bsv, ctx_buf, out_attn);

    dim3 ggrd(DD / TN, (BB * SS) / TM);         // 12 x 32
    gemm_out<<<ggrd, dim3(16, 16), 0, stream>>>(ctx_buf, Wo, bo, out_main);
}

// Round 8
// 510.498 us; speedup vs baseline: 1.6839x; 1.6839x over previous
//
#include <hip/hip_runtime.h>
#include <hip/hip_bf16.h>

typedef unsigned int uint32_ty;

// native vector types (HIP_vector_type not accepted by some builtins)
typedef float  nfloat2 __attribute__((ext_vector_type(2)));
typedef float  nfloat4 __attribute__((ext_vector_type(4)));
typedef int    nint4   __attribute__((ext_vector_type(4)));
typedef short  bf16x8  __attribute__((ext_vector_type(8)));   // 8 bf16 (4 VGPRs)
typedef float  f32x4   __attribute__((ext_vector_type(4)));   // MFMA acc
typedef unsigned short ushort4n __attribute__((ext_vector_type(4)));

// Problem constants
#define BB 4
#define SS 512
#define DD 768
#define HH 12
#define DHH 64
#define SDD 30

// padded LDS row stride (elements) for bf16 rows of length 512
#define LP 520

__device__ __forceinline__ float bfu(unsigned short u) {
    return __uint_as_float(((uint32_ty)u) << 16);
}
__device__ __forceinline__ unsigned short tobf(float f) {
    return __bfloat16_as_ushort(__float2bfloat16(f));
}
__device__ __forceinline__ void unp8(uint4 u, float* t) {
    t[0] = __uint_as_float(u.x << 16);
    t[1] = __uint_as_float(u.x & 0xFFFF0000u);
    t[2] = __uint_as_float(u.y << 16);
    t[3] = __uint_as_float(u.y & 0xFFFF0000u);
    t[4] = __uint_as_float(u.z << 16);
    t[5] = __uint_as_float(u.z & 0xFFFF0000u);
    t[6] = __uint_as_float(u.w << 16);
    t[7] = __uint_as_float(u.w & 0xFFFF0000u);
}
__device__ __forceinline__ void unp4(uint2 u, float* t) {
    t[0] = __uint_as_float(u.x << 16);
    t[1] = __uint_as_float(u.x & 0xFFFF0000u);
    t[2] = __uint_as_float(u.y << 16);
    t[3] = __uint_as_float(u.y & 0xFFFF0000u);
}

// ---------------------------------------------------------------------------
// K1: fused projection GEMMs, MFMA bf16 (f32 accumulate).  (R6-proven)
// Tile 64x64, BK=64. 4 waves, each a 32x32 quadrant (2x2 of 16x16 frags).
// z=0 -> q f32 (B,H,S,DH) scaled 1/8; z=1 -> kT bf16 (B,H,DH,S);
// z=2 -> v bf16 (B,H,S,DH).
// ---------------------------------------------------------------------------
#define MBM 64
#define MBN 64
#define MBK 64
#define LDK 72

__global__ __launch_bounds__(256) void gemm_proj3(
    const float* __restrict__ Xq, const float* __restrict__ Xk, const float* __restrict__ Xv,
    const float* __restrict__ Wq, const float* __restrict__ Wk, const float* __restrict__ Wv,
    const float* __restrict__ bq, const float* __restrict__ bk, const float* __restrict__ bv,
    float* __restrict__ oq, unsigned short* __restrict__ okT, unsigned short* __restrict__ ov)
{
    __shared__ unsigned short As[MBM][LDK];   // [m][k] bf16
    __shared__ unsigned short Bs[MBN][LDK];   // [n][k] bf16
    int z = blockIdx.z;
    const float* X = (z == 0) ? Xq : (z == 1) ? Xk : Xv;
    const float* W = (z == 0) ? Wq : (z == 1) ? Wk : Wv;
    const float* bias = (z == 0) ? bq : (z == 1) ? bk : bv;

    int tid = threadIdx.x;
    int lane = tid & 63, wave = tid >> 6;
    int m0 = blockIdx.y * MBM, n0 = blockIdx.x * MBN;
    int wm = (wave >> 1) * 32, wn = (wave & 1) * 32;
    int fr = lane & 15, fq = lane >> 4;

    f32x4 acc[2][2];
#pragma unroll
    for (int i = 0; i < 2; i++)
#pragma unroll
        for (int j = 0; j < 2; j++) acc[i][j] = (f32x4){0.f, 0.f, 0.f, 0.f};

    for (int k0 = 0; k0 < DD; k0 += MBK) {
#pragma unroll
        for (int rep = 0; rep < 4; rep++) {
            int i = tid + 256 * rep;
            int r = i >> 4, c4 = i & 15;
            float4 xv = *(const float4*)(X + (size_t)(m0 + r) * DD + k0 + 4 * c4);
            ushort4n pk = {tobf(xv.x), tobf(xv.y), tobf(xv.z), tobf(xv.w)};
            *(ushort4n*)&As[r][4 * c4] = pk;
        }
#pragma unroll
        for (int rep = 0; rep < 4; rep++) {
            int i = tid + 256 * rep;
            int r = i >> 4, c4 = i & 15;
            float4 wv = *(const float4*)(W + (size_t)(k0 + r) * DD + n0 + 4 * c4);
            Bs[4 * c4 + 0][r] = tobf(wv.x);
            Bs[4 * c4 + 1][r] = tobf(wv.y);
            Bs[4 * c4 + 2][r] = tobf(wv.z);
            Bs[4 * c4 + 3][r] = tobf(wv.w);
        }
        __syncthreads();
#pragma unroll
        for (int ks = 0; ks < 2; ks++) {
            bf16x8 a0 = *(bf16x8*)&As[wm + fr][ks * 32 + fq * 8];
            bf16x8 a1 = *(bf16x8*)&As[wm + 16 + fr][ks * 32 + fq * 8];
            bf16x8 b0 = *(bf16x8*)&Bs[wn + fr][ks * 32 + fq * 8];
            bf16x8 b1 = *(bf16x8*)&Bs[wn + 16 + fr][ks * 32 + fq * 8];
            acc[0][0] = __builtin_amdgcn_mfma_f32_16x16x32_bf16(a0, b0, acc[0][0], 0, 0, 0);
            acc[0][1] = __builtin_amdgcn_mfma_f32_16x16x32_bf16(a0, b1, acc[0][1], 0, 0, 0);
            acc[1][0] = __builtin_amdgcn_mfma_f32_16x16x32_bf16(a1, b0, acc[1][0], 0, 0, 0);
            acc[1][1] = __builtin_amdgcn_mfma_f32_16x16x32_bf16(a1, b1, acc[1][1], 0, 0, 0);
        }
        __syncthreads();
    }

    // C/D layout: col=lane&15, row=(lane>>4)*4+r (m89-verified)
#pragma unroll
    for (int i = 0; i < 2; i++) {
#pragma unroll
        for (int j = 0; j < 2; j++) {
            int n = n0 + wn + 16 * j + fr;
            int h = n >> 6, d = n & 63;
            float bn = bias[n];
            int mbase = m0 + wm + 16 * i + fq * 4;
            int b = mbase >> 9, sbase = mbase & 511;
            if (z == 1) {
                ushort4n pk;
#pragma unroll
                for (int r = 0; r < 4; r++) pk[r] = tobf(acc[i][j][r] + bn);
                *(ushort4n*)(okT + ((((size_t)b * HH + h) * DHH + d) * SS + sbase)) = pk;
            } else if (z == 0) {
#pragma unroll
                for (int r = 0; r < 4; r++)
                    oq[((((size_t)b * HH + h) * SS + sbase + r) * DHH + d)] =
                        (acc[i][j][r] + bn) * 0.125f;
            } else {
#pragma unroll
                for (int r = 0; r < 4; r++)
                    ov[((((size_t)b * HH + h) * SS + sbase + r) * DHH + d)] =
                        tobf(acc[i][j][r] + bn);
            }
        }
    }
}

// ---------------------------------------------------------------------------
// K3: output GEMM  out = ctx @ Wo + bo  — now MFMA bf16 (proj3 pattern),
// f32 accumulate, f32 output.
// ---------------------------------------------------------------------------
__global__ __launch_bounds__(256) void gemm_out(
    const float* __restrict__ Xf, const float* __restrict__ W,
    const float* __restrict__ bias, float* __restrict__ out)
{
    __shared__ unsigned short As[MBM][LDK];   // [m][k] bf16
    __shared__ unsigned short Bs[MBN][LDK];   // [n][k] bf16
    int tid = threadIdx.x;
    int lane = tid & 63, wave = tid >> 6;
    int m0 = blockIdx.y * MBM, n0 = blockIdx.x * MBN;
    int wm = (wave >> 1) * 32, wn = (wave & 1) * 32;
    int fr = lane & 15, fq = lane >> 4;

    f32x4 acc[2][2];
#pragma unroll
    for (int i = 0; i < 2; i++)
#pragma unroll
        for (int j = 0; j < 2; j++) acc[i][j] = (f32x4){0.f, 0.f, 0.f, 0.f};

    for (int k0 = 0; k0 < DD; k0 += MBK) {
#pragma unroll
        for (int rep = 0; rep < 4; rep++) {
            int i = tid + 256 * rep;
            int r = i >> 4, c4 = i & 15;
            float4 xv = *(const float4*)(Xf + (size_t)(m0 + r) * DD + k0 + 4 * c4);
            ushort4n pk = {tobf(xv.x), tobf(xv.y), tobf(xv.z), tobf(xv.w)};
            *(ushort4n*)&As[r][4 * c4] = pk;
        }
#pragma unroll
        for (int rep = 0; rep < 4; rep++) {
            int i = tid + 256 * rep;
            int r = i >> 4, c4 = i & 15;
            float4 wv = *(const float4*)(W + (size_t)(k0 + r) * DD + n0 + 4 * c4);
            Bs[4 * c4 + 0][r] = tobf(wv.x);
            Bs[4 * c4 + 1][r] = tobf(wv.y);
            Bs[4 * c4 + 2][r] = tobf(wv.z);
            Bs[4 * c4 + 3][r] = tobf(wv.w);
        }
        __syncthreads();
#pragma unroll
        for (int ks = 0; ks < 2; ks++) {
            bf16x8 a0 = *(bf16x8*)&As[wm + fr][ks * 32 + fq * 8];
            bf16x8 a1 = *(bf16x8*)&As[wm + 16 + fr][ks * 32 + fq * 8];
            bf16x8 b0 = *(bf16x8*)&Bs[wn + fr][ks * 32 + fq * 8];
            bf16x8 b1 = *(bf16x8*)&Bs[wn + 16 + fr][ks * 32 + fq * 8];
            acc[0][0] = __builtin_amdgcn_mfma_f32_16x16x32_bf16(a0, b0, acc[0][0], 0, 0, 0);
            acc[0][1] = __builtin_amdgcn_mfma_f32_16x16x32_bf16(a0, b1, acc[0][1], 0, 0, 0);
            acc[1][0] = __builtin_amdgcn_mfma_f32_16x16x32_bf16(a1, b0, acc[1][0], 0, 0, 0);
            acc[1][1] = __builtin_amdgcn_mfma_f32_16x16x32_bf16(a1, b1, acc[1][1], 0, 0, 0);
        }
        __syncthreads();
    }

#pragma unroll
    for (int i = 0; i < 2; i++) {
#pragma unroll
        for (int j = 0; j < 2; j++) {
            int n = n0 + wn + 16 * j + fr;
            float bn = bias[n];
            int mbase = m0 + wm + 16 * i + fq * 4;
#pragma unroll
            for (int r = 0; r < 4; r++)
                out[(size_t)(mbase + r) * DD + n] = acc[i][j][r] + bn;
        }
    }
}

// ---------------------------------------------------------------------------
// K2 (fused attention) v4: bf16 kT/v, R2 structure-load, XCD swizzle.
// (R5/R6-proven — 253 µs, VALUBusy 47%)
// ---------------------------------------------------------------------------
__global__ __launch_bounds__(256) void attn_fused(
    const float* __restrict__ q,          // (B,H,S,DH) f32
    const unsigned short* __restrict__ kT,// (B,H,DH,S) bf16
    const unsigned short* __restrict__ v, // (B,H,S,DH) bf16
    const float* __restrict__ structure,  // (B,S,S,30) f32
    const int* __restrict__ mask,         // (B,S,S) int32 0/1
    const float* __restrict__ Wsk,  // (30,64)
    const float* __restrict__ bsk,  // (64)
    const float* __restrict__ Wsv,  // (30,64)
    const float* __restrict__ bsv,  // (64)
    float* __restrict__ ctx,        // (B,S,D)
    float* __restrict__ top_attn)   // (B,S,S) f32
{
    __shared__ float qs[HH][DHH];               //  3072 B
    __shared__ unsigned short stT[SDD][LP];     // 31200 B  structure row, transposed, bf16
    __shared__ float qt_s[HH][SDD];             //  1440 B
    __shared__ float qb_s[HH];                  //    48 B
    __shared__ float astr_s[HH][SDD];           //  1440 B
    __shared__ unsigned short at[HH][LP];       // 12480 B  attn weights bf16 [h][k]

    int tid = threadIdx.x;
    int lane = tid & 63, wave = tid >> 6;

    // XCD-aware swizzle: blocks on one XCD share one batch's kT/v slab (1.5 MB < 4 MB L2)
    int blk = blockIdx.x;
    int xcd = blk & 7;
    int b = xcd >> 1;
    int qp = ((xcd & 1) << 8) | (blk >> 3);

    // --- load q rows for all heads ---
    for (int i = tid; i < HH * DHH; i += 256) {
        int h = i >> 6, d = i & 63;
        qs[h][d] = q[(((size_t)b * HH + h) * SS + qp) * DHH + d];
    }
    // --- load structure row (b,qp,:,:) f32 -> transposed bf16 LDS (R2 pattern) ---
    {
        const float* srow = structure + ((size_t)b * SS + qp) * (size_t)(SS * SDD);
        for (int k = tid; k < SS; k += 256) {
            const nfloat2* rp = (const nfloat2*)(srow + (size_t)k * SDD);
#pragma unroll
            for (int w = 0; w < 15; w++) {
                nfloat2 xv = __builtin_nontemporal_load(rp + w);
                stT[2 * w][k] = tobf(xv.x);
                stT[2 * w + 1][k] = tobf(xv.y);
            }
        }
    }
    __syncthreads();

    // --- qt[h][si] = qs[h] . Wsk[si]; qb[h] = qs[h] . bsk ---
    for (int i = tid; i < HH * SDD; i += 256) {
        int h = i / SDD, si = i % SDD;
        const float4* wp = (const float4*)(Wsk + si * DHH);
        const float4* qp4 = (const float4*)qs[h];
        float a = 0.f;
#pragma unroll
        for (int d4 = 0; d4 < 16; d4++) {
            float4 wv = wp[d4];
            float4 qv = qp4[d4];
            a += qv.x * wv.x + qv.y * wv.y + qv.z * wv.z + qv.w * wv.w;
        }
        qt_s[h][si] = a;
    }
    if (tid < HH) {
        const float4* bp = (const float4*)bsk;
        const float4* qp4 = (const float4*)qs[tid];
        float a = 0.f;
#pragma unroll
        for (int d4 = 0; d4 < 16; d4++) {
            float4 wv = bp[d4];
            float4 qv = qp4[d4];
            a += qv.x * wv.x + qv.y * wv.y + qv.z * wv.z + qv.w * wv.w;
        }
        qb_s[tid] = a;
    }
    __syncthreads();

    // --- scores: wave w -> heads 3w..3w+2, lane owns k = 8*lane..8*lane+7 ---
    int h0 = wave * 3;
    float attnv[3][8];
#pragma unroll
    for (int h = 0; h < 3; h++)
#pragma unroll
        for (int j = 0; j < 8; j++) attnv[h][j] = 0.f;

    // structure-score term: b128 reads of stT, broadcast qt
#pragma unroll 2
    for (int si = 0; si < SDD; si++) {
        uint4 sv4 = *(const uint4*)&stT[si][8 * lane];
        float t[8];
        unp8(sv4, t);
#pragma unroll
        for (int h = 0; h < 3; h++) {
            float qt = qt_s[h0 + h][si];
#pragma unroll
            for (int j = 0; j < 8; j++) attnv[h][j] += qt * t[j];
        }
    }

    // q.k term: bf16 kT, one uint4 = 8 k-values per d-row; fully coalesced
    {
        const unsigned short* kbase = kT + (((size_t)b * HH + h0) * DHH) * SS + 8 * lane;
#pragma unroll
        for (int h = 0; h < 3; h++) {
            const unsigned short* kp = kbase + (size_t)h * (DHH * SS);
            float acc[8] = {0.f, 0.f, 0.f, 0.f, 0.f, 0.f, 0.f, 0.f};
#pragma unroll 8
            for (int d = 0; d < DHH; d++) {
                float qd = qs[h0 + h][d];
                uint4 kv = *(const uint4*)(kp + (size_t)d * SS);
                float t[8];
                unp8(kv, t);
#pragma unroll
                for (int j = 0; j < 8; j++) acc[j] += qd * t[j];
            }
            float qb = qb_s[h0 + h];
#pragma unroll
            for (int j = 0; j < 8; j++) attnv[h][j] += acc[j] + qb;
        }
    }

    // mask
    {
        const int* mrow = mask + ((size_t)b * SS + qp) * SS + 8 * lane;
        nint4 m0v = __builtin_nontemporal_load((const nint4*)mrow);
        nint4 m1v = __builtin_nontemporal_load(((const nint4*)mrow) + 1);
        int mm[8] = {m0v.x, m0v.y, m0v.z, m0v.w, m1v.x, m1v.y, m1v.z, m1v.w};
#pragma unroll
        for (int h = 0; h < 3; h++)
#pragma unroll
            for (int j = 0; j < 8; j++)
                if (mm[j]) attnv[h][j] = -1e18f;
    }

    // --- softmax per head, in-wave ---
#pragma unroll
    for (int h = 0; h < 3; h++) {
        float m = attnv[h][0];
#pragma unroll
        for (int j = 1; j < 8; j++) m = fmaxf(m, attnv[h][j]);
#pragma unroll
        for (int off = 32; off > 0; off >>= 1) m = fmaxf(m, __shfl_xor(m, off));
        float l = 0.f;
#pragma unroll
        for (int j = 0; j < 8; j++) { attnv[h][j] = __expf(attnv[h][j] - m); l += attnv[h][j]; }
#pragma unroll
        for (int off = 32; off > 0; off >>= 1) l += __shfl_xor(l, off);
        float inv = 1.f / l;
        float a[8];
#pragma unroll
        for (int j = 0; j < 8; j++) a[j] = attnv[h][j] * inv;
        uint4 pk;
        pk.x = (uint32_ty)tobf(a[0]) | ((uint32_ty)tobf(a[1]) << 16);
        pk.y = (uint32_ty)tobf(a[2]) | ((uint32_ty)tobf(a[3]) << 16);
        pk.z = (uint32_ty)tobf(a[4]) | ((uint32_ty)tobf(a[5]) << 16);
        pk.w = (uint32_ty)tobf(a[6]) | ((uint32_ty)tobf(a[7]) << 16);
        *(uint4*)&at[h0 + h][8 * lane] = pk;
        if (h0 + h == 0) {
            float* tp = top_attn + ((size_t)b * SS + qp) * SS + 8 * lane;
            nfloat4 w0 = {a[0], a[1], a[2], a[3]};
            nfloat4 w1 = {a[4], a[5], a[6], a[7]};
            __builtin_nontemporal_store(w0, (nfloat4*)tp);
            __builtin_nontemporal_store(w1, ((nfloat4*)tp) + 1);
        }
    }
    __syncthreads();

    // --- astr[h][si] = sum_k attn[h][k] * structure[k][si] : all-b128 LDS ---
    if (tid < 180) {
        int h = tid / 15, sp = tid % 15;
        int si0 = 2 * sp, si1 = si0 + 1;
        float a0e = 0.f, a0o = 0.f, a1e = 0.f, a1o = 0.f;
#pragma unroll 2
        for (int j = 0; j < 64; j++) {
            uint4 av = *(const uint4*)&at[h][8 * j];
            uint4 s0 = *(const uint4*)&stT[si0][8 * j];
            uint4 s1 = *(const uint4*)&stT[si1][8 * j];
            float a[8], t0[8], t1[8];
            unp8(av, a); unp8(s0, t0); unp8(s1, t1);
#pragma unroll
            for (int t = 0; t < 8; t += 2) {
                a0e += a[t] * t0[t];     a0o += a[t + 1] * t0[t + 1];
                a1e += a[t] * t1[t];     a1o += a[t + 1] * t1[t + 1];
            }
        }
        astr_s[h][si0] = a0e + a0o;
        astr_s[h][si1] = a1e + a1o;
    }
    __syncthreads();

    // --- ctx: thread=(h, dq) computes 4 floats; attn@v (bf16 uint2 loads) + astr@Wsv + bsv ---
    if (tid < 192) {
        int h = tid >> 4, dq = tid & 15;
        const unsigned short* vp = v + ((size_t)b * HH + h) * (size_t)(SS * DHH) + 4 * dq;
        float4 ae; ae.x = ae.y = ae.z = ae.w = 0.f;
        float4 ao; ao.x = ao.y = ao.z = ao.w = 0.f;
#pragma unroll 2
        for (int j = 0; j < 64; j++) {
            uint4 av = *(const uint4*)&at[h][8 * j];
            float a[8];
            unp8(av, a);
            const unsigned short* vk = vp + (size_t)(8 * j) * DHH;
#pragma unroll
            for (int t = 0; t < 8; t += 2) {
                uint2 v0 = *(const uint2*)(vk + (size_t)t * DHH);
                uint2 v1 = *(const uint2*)(vk + (size_t)(t + 1) * DHH);
                float f0[4], f1[4];
                unp4(v0, f0); unp4(v1, f1);
                ae.x += a[t] * f0[0]; ae.y += a[t] * f0[1];
                ae.z += a[t] * f0[2]; ae.w += a[t] * f0[3];
                ao.x += a[t + 1] * f1[0]; ao.y += a[t + 1] * f1[1];
                ao.z += a[t + 1] * f1[2]; ao.w += a[t + 1] * f1[3];
            }
        }
        float4 sa = *(const float4*)(bsv + 4 * dq);
#pragma unroll
        for (int si = 0; si < SDD; si++) {
            float as = astr_s[h][si];
            float4 wv = *(const float4*)(Wsv + si * DHH + 4 * dq);
            sa.x += as * wv.x; sa.y += as * wv.y;
            sa.z += as * wv.z; sa.w += as * wv.w;
        }
        float4 outv;
        outv.x = ae.x + ao.x + sa.x;
        outv.y = ae.y + ao.y + sa.y;
        outv.z = ae.z + ao.z + sa.z;
        outv.w = ae.w + ao.w + sa.w;
        *(float4*)(ctx + ((size_t)b * SS + qp) * DD + h * DHH + 4 * dq) = outv;
    }
}

// ---------------------------------------------------------------------------
extern "C" void kernel_launch(void* const* d_in, const int* in_sizes, int n_in,
                              void* d_out, int out_size, void* d_ws, size_t ws_size,
                              hipStream_t stream)
{
    const float* key       = (const float*)d_in[0];
    const float* value     = (const float*)d_in[1];
    const float* query     = (const float*)d_in[2];
    const float* structure = (const float*)d_in[3];
    const int*   mask      = (const int*)d_in[4];
    const float* Wq  = (const float*)d_in[5];
    const float* bq  = (const float*)d_in[6];
    const float* Wk  = (const float*)d_in[7];
    const float* bk  = (const float*)d_in[8];
    const float* Wv  = (const float*)d_in[9];
    const float* bv  = (const float*)d_in[10];
    const float* Wsk = (const float*)d_in[11];
    const float* bsk = (const float*)d_in[12];
    const float* Wsv = (const float*)d_in[13];
    const float* bsv = (const float*)d_in[14];
    const float* Wo  = (const float*)d_in[15];
    const float* bo  = (const float*)d_in[16];

    float* out_main = (float*)d_out;                         // (B,S,D)
    float* out_attn = (float*)d_out + (size_t)BB * SS * DD;  // (B,S,S)

    float* ws = (float*)d_ws;
    float*          q_buf   = ws;                                  // (B,H,S,DH) f32
    unsigned short* kT_buf  = (unsigned short*)(ws + 1572864);     // (B,H,DH,S) bf16
    unsigned short* v_buf   = (unsigned short*)(ws + 2359296);     // (B,H,S,DH) bf16
    float*          ctx_buf = ws + 3145728;                        // (B,S,D) f32

    dim3 ggrd3(DD / MBN, (BB * SS) / MBM, 3);   // 12 x 32 x 3
    gemm_proj3<<<ggrd3, dim3(256), 0, stream>>>(query, key, value, Wq, Wk, Wv,
                                                bq, bk, bv, q_buf, kT_buf, v_buf);

    attn_fused<<<BB * SS, 256, 0, stream>>>(q_buf, kT_buf, v_buf, structure, mask,
                                            Wsk, bsk, Wsv, bsv, ctx_buf, out_attn);

    dim3 ggrd(DD / MBN, (BB * SS) / MBM);       // 12 x 32
    gemm_out<<<ggrd, dim3(256), 0, stream>>>(ctx_buf, Wo, bo, out_main);
}

// Round 9
// 476.453 us; speedup vs baseline: 1.8042x; 1.0715x over previous
//
#include <hip/hip_runtime.h>
#include <hip/hip_bf16.h>

typedef unsigned int uint32_ty;

// native vector types (HIP_vector_type not accepted by some builtins)
typedef float  nfloat2 __attribute__((ext_vector_type(2)));
typedef float  nfloat4 __attribute__((ext_vector_type(4)));
typedef int    nint4   __attribute__((ext_vector_type(4)));
typedef short  bf16x8  __attribute__((ext_vector_type(8)));   // 8 bf16 (4 VGPRs)
typedef float  f32x4   __attribute__((ext_vector_type(4)));   // MFMA acc
typedef unsigned short ushort4n __attribute__((ext_vector_type(4)));

// Problem constants
#define BB 4
#define SS 512
#define DD 768
#define HH 12
#define DHH 64
#define SDD 30

// padded LDS row stride (elements) for bf16 rows of length 512
#define LP 520

__device__ __forceinline__ float bfu(unsigned short u) {
    return __uint_as_float(((uint32_ty)u) << 16);
}
__device__ __forceinline__ unsigned short tobf(float f) {
    return __bfloat16_as_ushort(__float2bfloat16(f));
}
__device__ __forceinline__ uint32_ty pk2(float a, float b) {
    return ((uint32_ty)tobf(a)) | ((uint32_ty)tobf(b) << 16);
}
__device__ __forceinline__ void unp8(uint4 u, float* t) {
    t[0] = __uint_as_float(u.x << 16);
    t[1] = __uint_as_float(u.x & 0xFFFF0000u);
    t[2] = __uint_as_float(u.y << 16);
    t[3] = __uint_as_float(u.y & 0xFFFF0000u);
    t[4] = __uint_as_float(u.z << 16);
    t[5] = __uint_as_float(u.z & 0xFFFF0000u);
    t[6] = __uint_as_float(u.w << 16);
    t[7] = __uint_as_float(u.w & 0xFFFF0000u);
}
__device__ __forceinline__ void unp4(uint2 u, float* t) {
    t[0] = __uint_as_float(u.x << 16);
    t[1] = __uint_as_float(u.x & 0xFFFF0000u);
    t[2] = __uint_as_float(u.y << 16);
    t[3] = __uint_as_float(u.y & 0xFFFF0000u);
}

// ---------------------------------------------------------------------------
// P1: elementwise f32 -> bf16 for key/value inputs (8 elems/thread)
// ---------------------------------------------------------------------------
__global__ __launch_bounds__(256) void cvt_x(
    const float* __restrict__ k_in, const float* __restrict__ v_in,
    unsigned short* __restrict__ kb, unsigned short* __restrict__ vb)
{
    const float* in = blockIdx.z ? v_in : k_in;
    unsigned short* out = blockIdx.z ? vb : kb;
    size_t i = (size_t)blockIdx.x * 256 + threadIdx.x;   // 0..196607
    const float4* p = (const float4*)in;
    float4 a = p[2 * i], b = p[2 * i + 1];
    uint4 pk;
    pk.x = pk2(a.x, a.y); pk.y = pk2(a.z, a.w);
    pk.z = pk2(b.x, b.y); pk.w = pk2(b.z, b.w);
    ((uint4*)out)[i] = pk;
}

// ---------------------------------------------------------------------------
// P2: W (768x768 f32, [k][n]) -> WT (bf16, [n][k]) via LDS 64x64 tile.
// z selects {Wq, Wk, Wv, Wo}.
// ---------------------------------------------------------------------------
__global__ __launch_bounds__(256) void cvt_wT(
    const float* __restrict__ W0, const float* __restrict__ W1,
    const float* __restrict__ W2, const float* __restrict__ W3,
    unsigned short* __restrict__ T0, unsigned short* __restrict__ T1,
    unsigned short* __restrict__ T2, unsigned short* __restrict__ T3)
{
    __shared__ float tile[64][65];
    int z = blockIdx.z;
    const float* W = (z == 0) ? W0 : (z == 1) ? W1 : (z == 2) ? W2 : W3;
    unsigned short* T = (z == 0) ? T0 : (z == 1) ? T1 : (z == 2) ? T2 : T3;
    int k0 = blockIdx.y * 64, n0 = blockIdx.x * 64;
    int tid = threadIdx.x;
#pragma unroll
    for (int rep = 0; rep < 4; rep++) {
        int i = tid + 256 * rep;
        int r = i >> 4, c4 = i & 15;
        float4 wv = *(const float4*)(W + (size_t)(k0 + r) * DD + n0 + 4 * c4);
        tile[r][4 * c4 + 0] = wv.x; tile[r][4 * c4 + 1] = wv.y;
        tile[r][4 * c4 + 2] = wv.z; tile[r][4 * c4 + 3] = wv.w;
    }
    __syncthreads();
#pragma unroll
    for (int rep = 0; rep < 2; rep++) {
        int i = tid + 256 * rep;
        int n = i >> 3, kc = i & 7;
        uint4 pk;
        pk.x = pk2(tile[8 * kc + 0][n], tile[8 * kc + 1][n]);
        pk.y = pk2(tile[8 * kc + 2][n], tile[8 * kc + 3][n]);
        pk.z = pk2(tile[8 * kc + 4][n], tile[8 * kc + 5][n]);
        pk.w = pk2(tile[8 * kc + 6][n], tile[8 * kc + 7][n]);
        *(uint4*)(T + (size_t)(n0 + n) * DD + k0 + 8 * kc) = pk;
    }
}

// ---------------------------------------------------------------------------
// K1: fused projection GEMMs, MFMA bf16, pure-copy staging (prepacked inputs).
// z=0: A = query f32 (cvt in staging, q stays full-precision path);
// z=1/2: A = prepacked bf16 key/value.  B = prepacked transposed bf16 W.
// Outputs: z=0 -> q f32 (B,H,S,DH) scaled 1/8; z=1 -> kT bf16 (B,H,DH,S);
// z=2 -> v bf16 (B,H,S,DH).
// ---------------------------------------------------------------------------
#define MBM 64
#define MBN 64
#define MBK 64
#define LDK 72

__global__ __launch_bounds__(256) void gemm_proj3(
    const float* __restrict__ Xq,
    const unsigned short* __restrict__ Xkb, const unsigned short* __restrict__ Xvb,
    const unsigned short* __restrict__ WTq, const unsigned short* __restrict__ WTk,
    const unsigned short* __restrict__ WTv,
    const float* __restrict__ bq, const float* __restrict__ bk, const float* __restrict__ bv,
    float* __restrict__ oq, unsigned short* __restrict__ okT, unsigned short* __restrict__ ov)
{
    __shared__ unsigned short As[MBM][LDK];   // [m][k] bf16
    __shared__ unsigned short Bs[MBN][LDK];   // [n][k] bf16
    int z = blockIdx.z;
    const unsigned short* WT = (z == 0) ? WTq : (z == 1) ? WTk : WTv;
    const float* bias = (z == 0) ? bq : (z == 1) ? bk : bv;

    int tid = threadIdx.x;
    int lane = tid & 63, wave = tid >> 6;
    int m0 = blockIdx.y * MBM, n0 = blockIdx.x * MBN;
    int wm = (wave >> 1) * 32, wn = (wave & 1) * 32;
    int fr = lane & 15, fq = lane >> 4;

    f32x4 acc[2][2];
#pragma unroll
    for (int i = 0; i < 2; i++)
#pragma unroll
        for (int j = 0; j < 2; j++) acc[i][j] = (f32x4){0.f, 0.f, 0.f, 0.f};

    for (int k0 = 0; k0 < DD; k0 += MBK) {
        if (z == 0) {
#pragma unroll
            for (int rep = 0; rep < 4; rep++) {
                int i = tid + 256 * rep;
                int r = i >> 4, c4 = i & 15;
                float4 xv = *(const float4*)(Xq + (size_t)(m0 + r) * DD + k0 + 4 * c4);
                ushort4n pk = {tobf(xv.x), tobf(xv.y), tobf(xv.z), tobf(xv.w)};
                *(ushort4n*)&As[r][4 * c4] = pk;
            }
        } else {
            const unsigned short* Xb = (z == 1) ? Xkb : Xvb;
#pragma unroll
            for (int rep = 0; rep < 2; rep++) {
                int i = tid + 256 * rep;
                int r = i >> 3, c = i & 7;
                *(uint4*)&As[r][8 * c] =
                    *(const uint4*)(Xb + (size_t)(m0 + r) * DD + k0 + 8 * c);
            }
        }
#pragma unroll
        for (int rep = 0; rep < 2; rep++) {
            int i = tid + 256 * rep;
            int r = i >> 3, c = i & 7;
            *(uint4*)&Bs[r][8 * c] =
                *(const uint4*)(WT + (size_t)(n0 + r) * DD + k0 + 8 * c);
        }
        __syncthreads();
#pragma unroll
        for (int ks = 0; ks < 2; ks++) {
            bf16x8 a0 = *(bf16x8*)&As[wm + fr][ks * 32 + fq * 8];
            bf16x8 a1 = *(bf16x8*)&As[wm + 16 + fr][ks * 32 + fq * 8];
            bf16x8 b0 = *(bf16x8*)&Bs[wn + fr][ks * 32 + fq * 8];
            bf16x8 b1 = *(bf16x8*)&Bs[wn + 16 + fr][ks * 32 + fq * 8];
            acc[0][0] = __builtin_amdgcn_mfma_f32_16x16x32_bf16(a0, b0, acc[0][0], 0, 0, 0);
            acc[0][1] = __builtin_amdgcn_mfma_f32_16x16x32_bf16(a0, b1, acc[0][1], 0, 0, 0);
            acc[1][0] = __builtin_amdgcn_mfma_f32_16x16x32_bf16(a1, b0, acc[1][0], 0, 0, 0);
            acc[1][1] = __builtin_amdgcn_mfma_f32_16x16x32_bf16(a1, b1, acc[1][1], 0, 0, 0);
        }
        __syncthreads();
    }

    // C/D layout: col=lane&15, row=(lane>>4)*4+r (m89-verified)
#pragma unroll
    for (int i = 0; i < 2; i++) {
#pragma unroll
        for (int j = 0; j < 2; j++) {
            int n = n0 + wn + 16 * j + fr;
            int h = n >> 6, d = n & 63;
            float bn = bias[n];
            int mbase = m0 + wm + 16 * i + fq * 4;
            int b = mbase >> 9, sbase = mbase & 511;
            if (z == 1) {
                ushort4n pk;
#pragma unroll
                for (int r = 0; r < 4; r++) pk[r] = tobf(acc[i][j][r] + bn);
                *(ushort4n*)(okT + ((((size_t)b * HH + h) * DHH + d) * SS + sbase)) = pk;
            } else if (z == 0) {
#pragma unroll
                for (int r = 0; r < 4; r++)
                    oq[((((size_t)b * HH + h) * SS + sbase + r) * DHH + d)] =
                        (acc[i][j][r] + bn) * 0.125f;
            } else {
#pragma unroll
                for (int r = 0; r < 4; r++)
                    ov[((((size_t)b * HH + h) * SS + sbase + r) * DHH + d)] =
                        tobf(acc[i][j][r] + bn);
            }
        }
    }
}

// ---------------------------------------------------------------------------
// K3: output GEMM  out = ctx(bf16) @ WoT(bf16) + bo, MFMA, pure-copy staging.
// ---------------------------------------------------------------------------
__global__ __launch_bounds__(256) void gemm_out(
    const unsigned short* __restrict__ ctxb, const unsigned short* __restrict__ WoT,
    const float* __restrict__ bias, float* __restrict__ out)
{
    __shared__ unsigned short As[MBM][LDK];
    __shared__ unsigned short Bs[MBN][LDK];
    int tid = threadIdx.x;
    int lane = tid & 63, wave = tid >> 6;
    int m0 = blockIdx.y * MBM, n0 = blockIdx.x * MBN;
    int wm = (wave >> 1) * 32, wn = (wave & 1) * 32;
    int fr = lane & 15, fq = lane >> 4;

    f32x4 acc[2][2];
#pragma unroll
    for (int i = 0; i < 2; i++)
#pragma unroll
        for (int j = 0; j < 2; j++) acc[i][j] = (f32x4){0.f, 0.f, 0.f, 0.f};

    for (int k0 = 0; k0 < DD; k0 += MBK) {
#pragma unroll
        for (int rep = 0; rep < 2; rep++) {
            int i = tid + 256 * rep;
            int r = i >> 3, c = i & 7;
            *(uint4*)&As[r][8 * c] =
                *(const uint4*)(ctxb + (size_t)(m0 + r) * DD + k0 + 8 * c);
        }
#pragma unroll
        for (int rep = 0; rep < 2; rep++) {
            int i = tid + 256 * rep;
            int r = i >> 3, c = i & 7;
            *(uint4*)&Bs[r][8 * c] =
                *(const uint4*)(WoT + (size_t)(n0 + r) * DD + k0 + 8 * c);
        }
        __syncthreads();
#pragma unroll
        for (int ks = 0; ks < 2; ks++) {
            bf16x8 a0 = *(bf16x8*)&As[wm + fr][ks * 32 + fq * 8];
            bf16x8 a1 = *(bf16x8*)&As[wm + 16 + fr][ks * 32 + fq * 8];
            bf16x8 b0 = *(bf16x8*)&Bs[wn + fr][ks * 32 + fq * 8];
            bf16x8 b1 = *(bf16x8*)&Bs[wn + 16 + fr][ks * 32 + fq * 8];
            acc[0][0] = __builtin_amdgcn_mfma_f32_16x16x32_bf16(a0, b0, acc[0][0], 0, 0, 0);
            acc[0][1] = __builtin_amdgcn_mfma_f32_16x16x32_bf16(a0, b1, acc[0][1], 0, 0, 0);
            acc[1][0] = __builtin_amdgcn_mfma_f32_16x16x32_bf16(a1, b0, acc[1][0], 0, 0, 0);
            acc[1][1] = __builtin_amdgcn_mfma_f32_16x16x32_bf16(a1, b1, acc[1][1], 0, 0, 0);
        }
        __syncthreads();
    }

#pragma unroll
    for (int i = 0; i < 2; i++) {
#pragma unroll
        for (int j = 0; j < 2; j++) {
            int n = n0 + wn + 16 * j + fr;
            float bn = bias[n];
            int mbase = m0 + wm + 16 * i + fq * 4;
#pragma unroll
            for (int r = 0; r < 4; r++)
                out[(size_t)(mbase + r) * DD + n] = acc[i][j][r] + bn;
        }
    }
}

// ---------------------------------------------------------------------------
// K2 (fused attention): bf16 kT/v, R2 structure-load, XCD swizzle.
// Unchanged from R8 except ctx is written as bf16 (identical rounding to the
// conversion gemm_out's staging used to do — numerics unchanged).
// ---------------------------------------------------------------------------
__global__ __launch_bounds__(256) void attn_fused(
    const float* __restrict__ q,          // (B,H,S,DH) f32
    const unsigned short* __restrict__ kT,// (B,H,DH,S) bf16
    const unsigned short* __restrict__ v, // (B,H,S,DH) bf16
    const float* __restrict__ structure,  // (B,S,S,30) f32
    const int* __restrict__ mask,         // (B,S,S) int32 0/1
    const float* __restrict__ Wsk,  // (30,64)
    const float* __restrict__ bsk,  // (64)
    const float* __restrict__ Wsv,  // (30,64)
    const float* __restrict__ bsv,  // (64)
    unsigned short* __restrict__ ctxb,    // (B,S,D) bf16
    float* __restrict__ top_attn)   // (B,S,S) f32
{
    __shared__ float qs[HH][DHH];               //  3072 B
    __shared__ unsigned short stT[SDD][LP];     // 31200 B  structure row, transposed, bf16
    __shared__ float qt_s[HH][SDD];             //  1440 B
    __shared__ float qb_s[HH];                  //    48 B
    __shared__ float astr_s[HH][SDD];           //  1440 B
    __shared__ unsigned short at[HH][LP];       // 12480 B  attn weights bf16 [h][k]

    int tid = threadIdx.x;
    int lane = tid & 63, wave = tid >> 6;

    // XCD-aware swizzle: blocks on one XCD share one batch's kT/v slab (1.5 MB < 4 MB L2)
    int blk = blockIdx.x;
    int xcd = blk & 7;
    int b = xcd >> 1;
    int qp = ((xcd & 1) << 8) | (blk >> 3);

    // --- load q rows for all heads ---
    for (int i = tid; i < HH * DHH; i += 256) {
        int h = i >> 6, d = i & 63;
        qs[h][d] = q[(((size_t)b * HH + h) * SS + qp) * DHH + d];
    }
    // --- load structure row (b,qp,:,:) f32 -> transposed bf16 LDS (R2 pattern) ---
    {
        const float* srow = structure + ((size_t)b * SS + qp) * (size_t)(SS * SDD);
        for (int k = tid; k < SS; k += 256) {
            const nfloat2* rp = (const nfloat2*)(srow + (size_t)k * SDD);
#pragma unroll
            for (int w = 0; w < 15; w++) {
                nfloat2 xv = __builtin_nontemporal_load(rp + w);
                stT[2 * w][k] = tobf(xv.x);
                stT[2 * w + 1][k] = tobf(xv.y);
            }
        }
    }
    __syncthreads();

    // --- qt[h][si] = qs[h] . Wsk[si]; qb[h] = qs[h] . bsk ---
    for (int i = tid; i < HH * SDD; i += 256) {
        int h = i / SDD, si = i % SDD;
        const float4* wp = (const float4*)(Wsk + si * DHH);
        const float4* qp4 = (const float4*)qs[h];
        float a = 0.f;
#pragma unroll
        for (int d4 = 0; d4 < 16; d4++) {
            float4 wv = wp[d4];
            float4 qv = qp4[d4];
            a += qv.x * wv.x + qv.y * wv.y + qv.z * wv.z + qv.w * wv.w;
        }
        qt_s[h][si] = a;
    }
    if (tid < HH) {
        const float4* bp = (const float4*)bsk;
        const float4* qp4 = (const float4*)qs[tid];
        float a = 0.f;
#pragma unroll
        for (int d4 = 0; d4 < 16; d4++) {
            float4 wv = bp[d4];
            float4 qv = qp4[d4];
            a += qv.x * wv.x + qv.y * wv.y + qv.z * wv.z + qv.w * wv.w;
        }
        qb_s[tid] = a;
    }
    __syncthreads();

    // --- scores: wave w -> heads 3w..3w+2, lane owns k = 8*lane..8*lane+7 ---
    int h0 = wave * 3;
    float attnv[3][8];
#pragma unroll
    for (int h = 0; h < 3; h++)
#pragma unroll
        for (int j = 0; j < 8; j++) attnv[h][j] = 0.f;

    // structure-score term: b128 reads of stT, broadcast qt
#pragma unroll 2
    for (int si = 0; si < SDD; si++) {
        uint4 sv4 = *(const uint4*)&stT[si][8 * lane];
        float t[8];
        unp8(sv4, t);
#pragma unroll
        for (int h = 0; h < 3; h++) {
            float qt = qt_s[h0 + h][si];
#pragma unroll
            for (int j = 0; j < 8; j++) attnv[h][j] += qt * t[j];
        }
    }

    // q.k term: bf16 kT, one uint4 = 8 k-values per d-row; fully coalesced
    {
        const unsigned short* kbase = kT + (((size_t)b * HH + h0) * DHH) * SS + 8 * lane;
#pragma unroll
        for (int h = 0; h < 3; h++) {
            const unsigned short* kp = kbase + (size_t)h * (DHH * SS);
            float acc[8] = {0.f, 0.f, 0.f, 0.f, 0.f, 0.f, 0.f, 0.f};
#pragma unroll 8
            for (int d = 0; d < DHH; d++) {
                float qd = qs[h0 + h][d];
                uint4 kv = *(const uint4*)(kp + (size_t)d * SS);
                float t[8];
                unp8(kv, t);
#pragma unroll
                for (int j = 0; j < 8; j++) acc[j] += qd * t[j];
            }
            float qb = qb_s[h0 + h];
#pragma unroll
            for (int j = 0; j < 8; j++) attnv[h][j] += acc[j] + qb;
        }
    }

    // mask
    {
        const int* mrow = mask + ((size_t)b * SS + qp) * SS + 8 * lane;
        nint4 m0v = __builtin_nontemporal_load((const nint4*)mrow);
        nint4 m1v = __builtin_nontemporal_load(((const nint4*)mrow) + 1);
        int mm[8] = {m0v.x, m0v.y, m0v.z, m0v.w, m1v.x, m1v.y, m1v.z, m1v.w};
#pragma unroll
        for (int h = 0; h < 3; h++)
#pragma unroll
            for (int j = 0; j < 8; j++)
                if (mm[j]) attnv[h][j] = -1e18f;
    }

    // --- softmax per head, in-wave ---
#pragma unroll
    for (int h = 0; h < 3; h++) {
        float m = attnv[h][0];
#pragma unroll
        for (int j = 1; j < 8; j++) m = fmaxf(m, attnv[h][j]);
#pragma unroll
        for (int off = 32; off > 0; off >>= 1) m = fmaxf(m, __shfl_xor(m, off));
        float l = 0.f;
#pragma unroll
        for (int j = 0; j < 8; j++) { attnv[h][j] = __expf(attnv[h][j] - m); l += attnv[h][j]; }
#pragma unroll
        for (int off = 32; off > 0; off >>= 1) l += __shfl_xor(l, off);
        float inv = 1.f / l;
        float a[8];
#pragma unroll
        for (int j = 0; j < 8; j++) a[j] = attnv[h][j] * inv;
        uint4 pk;
        pk.x = (uint32_ty)tobf(a[0]) | ((uint32_ty)tobf(a[1]) << 16);
        pk.y = (uint32_ty)tobf(a[2]) | ((uint32_ty)tobf(a[3]) << 16);
        pk.z = (uint32_ty)tobf(a[4]) | ((uint32_ty)tobf(a[5]) << 16);
        pk.w = (uint32_ty)tobf(a[6]) | ((uint32_ty)tobf(a[7]) << 16);
        *(uint4*)&at[h0 + h][8 * lane] = pk;
        if (h0 + h == 0) {
            float* tp = top_attn + ((size_t)b * SS + qp) * SS + 8 * lane;
            nfloat4 w0 = {a[0], a[1], a[2], a[3]};
            nfloat4 w1 = {a[4], a[5], a[6], a[7]};
            __builtin_nontemporal_store(w0, (nfloat4*)tp);
            __builtin_nontemporal_store(w1, ((nfloat4*)tp) + 1);
        }
    }
    __syncthreads();

    // --- astr[h][si] = sum_k attn[h][k] * structure[k][si] : all-b128 LDS ---
    if (tid < 180) {
        int h = tid / 15, sp = tid % 15;
        int si0 = 2 * sp, si1 = si0 + 1;
        float a0e = 0.f, a0o = 0.f, a1e = 0.f, a1o = 0.f;
#pragma unroll 2
        for (int j = 0; j < 64; j++) {
            uint4 av = *(const uint4*)&at[h][8 * j];
            uint4 s0 = *(const uint4*)&stT[si0][8 * j];
            uint4 s1 = *(const uint4*)&stT[si1][8 * j];
            float a[8], t0[8], t1[8];
            unp8(av, a); unp8(s0, t0); unp8(s1, t1);
#pragma unroll
            for (int t = 0; t < 8; t += 2) {
                a0e += a[t] * t0[t];     a0o += a[t + 1] * t0[t + 1];
                a1e += a[t] * t1[t];     a1o += a[t + 1] * t1[t + 1];
            }
        }
        astr_s[h][si0] = a0e + a0o;
        astr_s[h][si1] = a1e + a1o;
    }
    __syncthreads();

    // --- ctx: thread=(h, dq) computes 4 floats; attn@v + astr@Wsv + bsv; bf16 out ---
    if (tid < 192) {
        int h = tid >> 4, dq = tid & 15;
        const unsigned short* vp = v + ((size_t)b * HH + h) * (size_t)(SS * DHH) + 4 * dq;
        float4 ae; ae.x = ae.y = ae.z = ae.w = 0.f;
        float4 ao; ao.x = ao.y = ao.z = ao.w = 0.f;
#pragma unroll 2
        for (int j = 0; j < 64; j++) {
            uint4 av = *(const uint4*)&at[h][8 * j];
            float a[8];
            unp8(av, a);
            const unsigned short* vk = vp + (size_t)(8 * j) * DHH;
#pragma unroll
            for (int t = 0; t < 8; t += 2) {
                uint2 v0 = *(const uint2*)(vk + (size_t)t * DHH);
                uint2 v1 = *(const uint2*)(vk + (size_t)(t + 1) * DHH);
                float f0[4], f1[4];
                unp4(v0, f0); unp4(v1, f1);
                ae.x += a[t] * f0[0]; ae.y += a[t] * f0[1];
                ae.z += a[t] * f0[2]; ae.w += a[t] * f0[3];
                ao.x += a[t + 1] * f1[0]; ao.y += a[t + 1] * f1[1];
                ao.z += a[t + 1] * f1[2]; ao.w += a[t + 1] * f1[3];
            }
        }
        float4 sa = *(const float4*)(bsv + 4 * dq);
#pragma unroll
        for (int si = 0; si < SDD; si++) {
            float as = astr_s[h][si];
            float4 wv = *(const float4*)(Wsv + si * DHH + 4 * dq);
            sa.x += as * wv.x; sa.y += as * wv.y;
            sa.z += as * wv.z; sa.w += as * wv.w;
        }
        ushort4n co;
        co[0] = tobf(ae.x + ao.x + sa.x);
        co[1] = tobf(ae.y + ao.y + sa.y);
        co[2] = tobf(ae.z + ao.z + sa.z);
        co[3] = tobf(ae.w + ao.w + sa.w);
        *(ushort4n*)(ctxb + ((size_t)b * SS + qp) * DD + h * DHH + 4 * dq) = co;
    }
}

// ---------------------------------------------------------------------------
extern "C" void kernel_launch(void* const* d_in, const int* in_sizes, int n_in,
                              void* d_out, int out_size, void* d_ws, size_t ws_size,
                              hipStream_t stream)
{
    const float* key       = (const float*)d_in[0];
    const float* value     = (const float*)d_in[1];
    const float* query     = (const float*)d_in[2];
    const float* structure = (const float*)d_in[3];
    const int*   mask      = (const int*)d_in[4];
    const float* Wq  = (const float*)d_in[5];
    const float* bq  = (const float*)d_in[6];
    const float* Wk  = (const float*)d_in[7];
    const float* bk  = (const float*)d_in[8];
    const float* Wv  = (const float*)d_in[9];
    const float* bv  = (const float*)d_in[10];
    const float* Wsk = (const float*)d_in[11];
    const float* bsk = (const float*)d_in[12];
    const float* Wsv = (const float*)d_in[13];
    const float* bsv = (const float*)d_in[14];
    const float* Wo  = (const float*)d_in[15];
    const float* bo  = (const float*)d_in[16];

    float* out_main = (float*)d_out;                         // (B,S,D)
    float* out_attn = (float*)d_out + (size_t)BB * SS * DD;  // (B,S,S)

    // workspace layout (u16 units); ctx aliases Xb_k (dead after proj3)
    unsigned short* u = (unsigned short*)d_ws;
    unsigned short* Xb_k  = u;                 // 1,572,864 u16
    unsigned short* Xb_v  = u + 1572864;       // 1,572,864
    unsigned short* WT_q  = u + 3145728;       //   589,824
    unsigned short* WT_k  = u + 3735552;
    unsigned short* WT_v  = u + 4325376;
    unsigned short* WT_o  = u + 4915200;
    unsigned short* kT_b  = u + 5505024;       // 1,572,864
    unsigned short* v_b   = u + 7077888;       // 1,572,864
    float*          q_buf = (float*)(u + 8650752);  // 1,572,864 f32
    unsigned short* ctx_b = Xb_k;              // alias, live after proj3

    // P1: key/value -> bf16   (1,572,864/8/256 = 768 blocks)
    cvt_x<<<dim3(768, 1, 2), dim3(256), 0, stream>>>(key, value, Xb_k, Xb_v);
    // P2: W -> transposed bf16
    cvt_wT<<<dim3(12, 12, 4), dim3(256), 0, stream>>>(Wq, Wk, Wv, Wo,
                                                      WT_q, WT_k, WT_v, WT_o);

    dim3 ggrd3(DD / MBN, (BB * SS) / MBM, 3);   // 12 x 32 x 3
    gemm_proj3<<<ggrd3, dim3(256), 0, stream>>>(query, Xb_k, Xb_v,
                                                WT_q, WT_k, WT_v,
                                                bq, bk, bv, q_buf, kT_b, v_b);

    attn_fused<<<BB * SS, 256, 0, stream>>>(q_buf, kT_b, v_b, structure, mask,
                                            Wsk, bsk, Wsv, bsv, ctx_b, out_attn);

    dim3 ggrd(DD / MBN, (BB * SS) / MBM);       // 12 x 32
    gemm_out<<<ggrd, dim3(256), 0, stream>>>(ctx_b, WT_o, bo, out_main);
}